// Round 9
// baseline (140.241 us; speedup 1.0000x reference)
//
#include <hip/hip_runtime.h>
#include <hip/hip_bf16.h>

__device__ __forceinline__ float lrelu(float x) { return x >= 0.f ? x : 0.01f * x; }

// k_flag: flag[n] = 1 iff some edge has tgt == n. Idempotent dword store, no atomics.
__global__ __launch_bounds__(256) void k_flag(
    const int* __restrict__ tgt, unsigned int* __restrict__ flag, int E) {
  const int i = blockIdx.x * blockDim.x + threadIdx.x;
  const int stride = gridDim.x * blockDim.x;
  for (int e = i; e < E; e += stride) flag[tgt[e]] = 1u;
}

// k3: out[n,:] = flag[n] ? lrelu(x[n]@W_out + b_out) : 0.
// R8 counters showed VGPR_Count=36: the compiler rematerialized the 64
// loop-invariant weight loads inside the node loop (serial L1-hit -> FMA
// chain, 47us). The empty asm "+v" pins force the weights to stay resident
// in VGPRs (opaque def cannot be rematerialized). 2 nodes/iter for ILP.
__global__ __launch_bounds__(256) void k3_out(
    const float* __restrict__ x, const float* __restrict__ W_out,
    const float* __restrict__ b_out, const unsigned int* __restrict__ flag,
    float* __restrict__ out, int N) {
  const int lane = threadIdx.x & 63;
  float wo[64];
#pragma unroll
  for (int k = 0; k < 64; ++k) wo[k] = W_out[k * 64 + lane];
#pragma unroll
  for (int k = 0; k < 64; ++k) asm volatile("" : "+v"(wo[k]));  // pin in VGPRs
  const float bo = b_out[lane];
  const int wid = (int)((blockIdx.x * blockDim.x + threadIdx.x) >> 6);
  const int nw  = (int)((gridDim.x * blockDim.x) >> 6);
  const int nPairs = N >> 1;  // N is even (100000)
  for (int p = wid; p < nPairs; p += nw) {
    const int n = __builtin_amdgcn_readfirstlane(p << 1);
    const float4* xr0 = (const float4*)(x + (size_t)n * 64);
    const float4* xr1 = (const float4*)(x + (size_t)(n + 1) * 64);
    float acc0 = bo, acc1 = bo;
#pragma unroll
    for (int q = 0; q < 16; ++q) {
      const float4 a = xr0[q];
      const float4 b = xr1[q];
      acc0 = fmaf(a.x, wo[4*q+0], acc0);  acc1 = fmaf(b.x, wo[4*q+0], acc1);
      acc0 = fmaf(a.y, wo[4*q+1], acc0);  acc1 = fmaf(b.y, wo[4*q+1], acc1);
      acc0 = fmaf(a.z, wo[4*q+2], acc0);  acc1 = fmaf(b.z, wo[4*q+2], acc1);
      acc0 = fmaf(a.w, wo[4*q+3], acc0);  acc1 = fmaf(b.w, wo[4*q+3], acc1);
    }
    const float r0 = flag[n]     ? 1.f : 0.f;
    const float r1 = flag[n + 1] ? 1.f : 0.f;
    out[(size_t)n * 64 + lane]       = lrelu(acc0 * r0);
    out[(size_t)(n + 1) * 64 + lane] = lrelu(acc1 * r1);
  }
}

extern "C" void kernel_launch(void* const* d_in, const int* in_sizes, int n_in,
                              void* d_out, int out_size, void* d_ws, size_t ws_size,
                              hipStream_t stream) {
  const float* x     = (const float*)d_in[0];
  const int*   tgt   = (const int*)d_in[2];
  const float* W_out = (const float*)d_in[7];
  const float* b_out = (const float*)d_in[8];
  float* out = (float*)d_out;

  const int N = in_sizes[0] / 64;
  const int E = in_sizes[1];

  unsigned int* flag = (unsigned int*)d_ws;  // N dwords

  (void)hipMemsetAsync(flag, 0, (size_t)N * sizeof(unsigned int), stream);
  k_flag<<<2048, 256, 0, stream>>>(tgt, flag, E);
  k3_out<<<2048, 256, 0, stream>>>(x, W_out, b_out, flag, out, N);
}